// Round 4
// baseline (61.584 us; speedup 1.0000x reference)
//
#include <hip/hip_runtime.h>
#include <math.h>

#define NN 4096
#define NT 512           // threads; NT*8 == NN exactly (8 waves on one CU)
#define NWAVE (NT / 64)  // 8 waves
#define MAXC 512         // candidate cap (expected K ~ 3-6; conservative)

// sig2 exactly as reference: sig = sqrt(-2/log(1-avg^2)); sig2 = sig*sig
__device__ __forceinline__ float sig2_of_sum(float s) {
    float avg = s / 200.0f;
    float v = -2.0f / logf(1.0f - avg * avg);
    float sg = sqrtf(v);
    return sg * sg;
}

// merge (b1,b2) two-smallest into (a1,a2)
__device__ __forceinline__ void merge2min(float& a1, float& a2, float b1, float b2) {
    float lo = fminf(a1, b1);
    float hi = fmaxf(a1, b1);
    a1 = lo;
    a2 = fminf(hi, fminf(a2, b2));
}
__device__ __forceinline__ void merge2max(float& a1, float& a2, float b1, float b2) {
    float hi = fmaxf(a1, b1);
    float lo = fminf(a1, b1);
    a1 = hi;
    a2 = fmaxf(lo, fmaxf(a2, b2));
}

__global__ __launch_bounds__(NT) void ENCELDDT_fused(
        const float* __restrict__ sigmas,
        const float* __restrict__ y,
        const float* __restrict__ py,
        float* __restrict__ out) {
    __shared__ float wm1[NWAVE], wm2[NWAVE], wM1[NWAVE], wM2[NWAVE];
    __shared__ float s_scal[3];          // m1, begin, interval
    __shared__ float p1[NWAVE], p2[NWAVE], p3[NWAVE];
    __shared__ int   s_cand[MAXC];       // candidate indices
    __shared__ float s_cval[MAXC];       // candidate sigma values (avoid re-fetch)
    __shared__ int   s_K;

    const int t    = threadIdx.x;
    const int lane = t & 63;
    const int wave = t >> 6;
    if (t == 0) s_K = 0;

    // ---- Phase 1: load 8 sigmas/thread (two float4, kept in registers) ----
    const float4 va = reinterpret_cast<const float4*>(sigmas)[t];
    const float4 vb = reinterpret_cast<const float4*>(sigmas)[t + NT];

    float m1, m2, M1, M2;
    m1 = va.x; m2 = INFINITY; M1 = va.x; M2 = -INFINITY;
    merge2min(m1, m2, va.y, INFINITY);  merge2max(M1, M2, va.y, -INFINITY);
    merge2min(m1, m2, va.z, INFINITY);  merge2max(M1, M2, va.z, -INFINITY);
    merge2min(m1, m2, va.w, INFINITY);  merge2max(M1, M2, va.w, -INFINITY);
    merge2min(m1, m2, vb.x, INFINITY);  merge2max(M1, M2, vb.x, -INFINITY);
    merge2min(m1, m2, vb.y, INFINITY);  merge2max(M1, M2, vb.y, -INFINITY);
    merge2min(m1, m2, vb.z, INFINITY);  merge2max(M1, M2, vb.z, -INFINITY);
    merge2min(m1, m2, vb.w, INFINITY);  merge2max(M1, M2, vb.w, -INFINITY);

    // wave-level butterfly (64 lanes)
    #pragma unroll
    for (int mask = 1; mask < 64; mask <<= 1) {
        float b1 = __shfl_xor(m1, mask);
        float b2 = __shfl_xor(m2, mask);
        merge2min(m1, m2, b1, b2);
        float c1 = __shfl_xor(M1, mask);
        float c2 = __shfl_xor(M2, mask);
        merge2max(M1, M2, c1, c2);
    }
    if (lane == 0) { wm1[wave] = m1; wm2[wave] = m2; wM1[wave] = M1; wM2[wave] = M2; }
    __syncthreads();   // barrier 1 (also covers s_K init)

    if (wave == 0) {
        float a1 = (lane < NWAVE) ? wm1[lane] : INFINITY;
        float a2 = (lane < NWAVE) ? wm2[lane] : INFINITY;
        float c1 = (lane < NWAVE) ? wM1[lane] : -INFINITY;
        float c2 = (lane < NWAVE) ? wM2[lane] : -INFINITY;
        #pragma unroll
        for (int mask = 1; mask < 8; mask <<= 1) {   // only 8 partials
            float b1 = __shfl_xor(a1, mask);
            float b2 = __shfl_xor(a2, mask);
            merge2min(a1, a2, b1, b2);
            float d1 = __shfl_xor(c1, mask);
            float d2 = __shfl_xor(c2, mask);
            merge2max(c1, c2, d1, d2);
        }
        if (lane == 0) {
            // sig2 strictly decreasing in sigma sum:
            float begin    = sig2_of_sum(c1 + c2);   // min of sig2 (max sums)
            float endv     = sig2_of_sum(a1 + a2);   // max of sig2 (min sums)
            float interval = (endv - begin) / 10.0f;
            s_scal[0] = a1;        // global min sigma
            s_scal[1] = begin;
            s_scal[2] = interval;
        }
    }
    __syncthreads();   // barrier 2

    const float gm1      = s_scal[0];
    const float begin    = s_scal[1];
    const float interval = s_scal[2];

    // ---- Phase 2: candidate test on the 8 register-held values ----
    // i can be in a bin-9 pair only if its best partner (global min sigma)
    // reaches bin 9 (with slack). Exact membership re-tested per pair.
    {
        float vs[8] = {va.x, va.y, va.z, va.w, vb.x, vb.y, vb.z, vb.w};
        #pragma unroll
        for (int q = 0; q < 8; ++q) {
            float x = (sig2_of_sum(vs[q] + gm1) - begin) / interval;
            if (x >= 9.0f - 1e-3f) {
                int k = atomicAdd(&s_K, 1);
                if (k < MAXC) {
                    s_cand[k] = (q < 4 ? t : t + NT) * 4 + (q & 3);
                    s_cval[k] = vs[q];
                }
            }
        }
    }
    __syncthreads();   // barrier 3

    const int K = (s_K < MAXC) ? s_K : MAXC;

    // ---- Phase 3: exact pair loop over K*K ordered pairs ----
    float ssig2 = 0.0f, str2 = 0.0f, cntf = 0.0f;
    const int total = K * K;
    for (int idx = t; idx < total; idx += NT) {
        int a = idx / K;
        int b = idx - a * K;
        if (a == b) continue;          // off-diagonal: i != j
        int i = s_cand[a];
        int j = s_cand[b];

        float s2 = sig2_of_sum(s_cval[a] + s_cval[b]);
        float x  = (s2 - begin) / interval;
        // bin = clip(floor(x),0,9); membership in bin 9 <=> x >= 9.0f
        if (x >= 9.0f) {
            float dx = y[3 * i]     - y[3 * j];
            float dy = y[3 * i + 1] - y[3 * j + 1];
            float dz = y[3 * i + 2] - y[3 * j + 2];
            float dgt = sqrtf((dx * dx + dy * dy) + dz * dz);
            dx = py[3 * i]     - py[3 * j];
            dy = py[3 * i + 1] - py[3 * j + 1];
            dz = py[3 * i + 2] - py[3 * j + 2];
            float dpd = sqrtf((dx * dx + dy * dy) + dz * dz);
            float tr = dgt - dpd;
            ssig2 += s2;
            str2  += tr * tr;
            cntf  += 1.0f;
        }
    }

    // wave butterfly sum
    #pragma unroll
    for (int mask = 1; mask < 64; mask <<= 1) {
        ssig2 += __shfl_xor(ssig2, mask);
        str2  += __shfl_xor(str2,  mask);
        cntf  += __shfl_xor(cntf,  mask);
    }
    if (lane == 0) { p1[wave] = ssig2; p2[wave] = str2; p3[wave] = cntf; }
    __syncthreads();   // barrier 4

    if (wave == 0 && lane == 0) {
        float a = 0.0f, b = 0.0f, c = 0.0f;
        #pragma unroll
        for (int w = 0; w < NWAVE; ++w) { a += p1[w]; b += p2[w]; c += p3[w]; }
        float mvar = sqrtf(a / c);
        float rmse = sqrtf(b / c);
        out[0] = fabsf(mvar - rmse) / mvar;
    }
}

extern "C" void kernel_launch(void* const* d_in, const int* in_sizes, int n_in,
                              void* d_out, int out_size, void* d_ws, size_t ws_size,
                              hipStream_t stream) {
    const float* sigmas = (const float*)d_in[0];
    const float* y      = (const float*)d_in[1];
    const float* py     = (const float*)d_in[2];
    float* out = (float*)d_out;

    ENCELDDT_fused<<<1, NT, 0, stream>>>(sigmas, y, py, out);
}